// Round 1
// baseline (487.428 us; speedup 1.0000x reference)
//
#include <hip/hip_runtime.h>

// Problem constants (from reference)
#define B_     8
#define L_DEC_ 256
#define V_     32000
#define L_SRC_ 512
#define V_EXT_ 32128

#define V4_    (V_ / 4)      // 8000 float4 per dist row
#define VE4_   (V_EXT_ / 4)  // 8032 float4 per out row

// Kernel 1: out[b,t,v] = p_gen[b,t] * (v < V ? dist[b,t,v] : 0)
// One (b,t) row per blockIdx.y; float4 vectorized along v.
__global__ __launch_bounds__(256) void copynet_init(
    const float* __restrict__ dist,   // [B, L_DEC, V]
    const float* __restrict__ p_gen,  // [B, L_DEC, 1]
    float* __restrict__ out)          // [B, L_DEC, V_EXT]
{
    const int row  = blockIdx.y;                         // b*L_DEC + t
    const int col4 = blockIdx.x * blockDim.x + threadIdx.x;
    if (col4 >= VE4_) return;

    const float pg = p_gen[row];
    float4 r;
    if (col4 < V4_) {
        const float4 d = ((const float4*)dist)[(size_t)row * V4_ + col4];
        r.x = pg * d.x; r.y = pg * d.y; r.z = pg * d.z; r.w = pg * d.w;
    } else {
        r = make_float4(0.f, 0.f, 0.f, 0.f);             // pad region
    }
    ((float4*)out)[(size_t)row * VE4_ + col4] = r;
}

// Kernel 2: copyp scatter-add
// out[b,t,pointer[b,s]] += (1 - p_gen[b,t]) * alpha[b,s,t]
// One block per (b,s); thread t covers L_DEC. alpha[b,s,:] is contiguous -> coalesced.
__global__ __launch_bounds__(256) void copynet_scatter(
    const float* __restrict__ alph,    // [B, L_SRC, L_DEC]
    const float* __restrict__ p_gen,   // [B, L_DEC, 1]
    const int*   __restrict__ pointer, // [B, L_SRC]
    float* __restrict__ out)           // [B, L_DEC, V_EXT]
{
    const int bs = blockIdx.x;          // b*L_SRC + s
    const int b  = bs >> 9;             // / L_SRC (512)
    const int t  = threadIdx.x;         // 0..L_DEC-1

    const int   v    = pointer[bs];     // wave-uniform (broadcast via cache)
    const float a    = alph[(size_t)bs * L_DEC_ + t];
    const float coef = 1.0f - p_gen[b * L_DEC_ + t];

    atomicAdd(out + (size_t)(b * L_DEC_ + t) * V_EXT_ + v, coef * a);
}

extern "C" void kernel_launch(void* const* d_in, const int* in_sizes, int n_in,
                              void* d_out, int out_size, void* d_ws, size_t ws_size,
                              hipStream_t stream)
{
    const float* dist    = (const float*)d_in[0]; // (B, L_DEC, V)
    const float* p_gen   = (const float*)d_in[1]; // (B, L_DEC, 1)
    const float* alph    = (const float*)d_in[2]; // (B, L_SRC, L_DEC)
    // d_in[3] = batch_vocab (only shape used)
    const int*   pointer = (const int*)d_in[4];   // (B, L_SRC)
    float* out = (float*)d_out;                   // (B, L_DEC, V_EXT)

    // Kernel 1: 2048 rows x 8032 float4; 32 blocks of 256 threads per row
    dim3 grid1((VE4_ + 255) / 256, B_ * L_DEC_);
    copynet_init<<<grid1, 256, 0, stream>>>(dist, p_gen, out);

    // Kernel 2: one block per (b, s)
    copynet_scatter<<<B_ * L_SRC_, 256, 0, stream>>>(alph, p_gen, pointer, out);
}

// Round 2
// 438.976 us; speedup vs baseline: 1.1104x; 1.1104x over previous
//
#include <hip/hip_runtime.h>

// Problem constants (from reference)
#define B_     8
#define L_DEC_ 256
#define V_     32000
#define L_SRC_ 512
#define V_EXT_ 32128

#define V4_    (V_ / 4)      // 8000 float4 per dist row
#define VE4_   (V_EXT_ / 4)  // 8032 float4 per out row

#define HALF_  16064         // half of V_EXT_ (fp32 count) -> 62.75 KB LDS
#define HALF4_ (HALF_ / 4)   // 4016 float4 per half

// Fused kernel: one block per (b,t) output row.
//   out[b,t,v] = p_gen[b,t]*dist[b,t,v](v<V) + (1-p_gen[b,t])*copyp[b,t,v]
//   copyp[b,t,v] = sum_{s: pointer[b,s]==v} alpha[b,s,t]
// The copyp scatter (512 entries) is accumulated in LDS, vocab split in two
// halves to fit the 64 KB static-shared limit; scatter runs twice, predicated.
__global__ __launch_bounds__(512) void copynet_fused(
    const float* __restrict__ dist,    // [B, L_DEC, V]
    const float* __restrict__ p_gen,   // [B, L_DEC, 1]
    const float* __restrict__ alph,    // [B, L_SRC, L_DEC]
    const int*   __restrict__ pointer, // [B, L_SRC]
    float* __restrict__ out)           // [B, L_DEC, V_EXT]
{
    __shared__ float cp[HALF_];        // 62.75 KB -> 2 blocks/CU

    const int row = blockIdx.x;        // b*L_DEC + t  (t fastest -> alpha L2 reuse)
    const int b   = row >> 8;          // / L_DEC
    const int t   = row & (L_DEC_ - 1);
    const int tid = threadIdx.x;       // 0..511

    const float pg   = p_gen[row];     // wave-uniform broadcast
    const float coef = 1.0f - pg;

    // This thread's scatter entry: s == tid (L_SRC == blockDim == 512)
    const int   sIdx = b * L_SRC_ + tid;
    const int   v    = pointer[sIdx];
    const float val  = coef * alph[(size_t)sIdx * L_DEC_ + t];

    const float4* dist4 = (const float4*)(dist + (size_t)row * V_);
    float4*       out4  = (float4*)(out + (size_t)row * V_EXT_);
    float4*       cp4   = (float4*)cp;

#pragma unroll
    for (int h = 0; h < 2; ++h) {
        // zero this half's accumulator
        for (int i = tid; i < HALF4_; i += 512)
            cp4[i] = make_float4(0.f, 0.f, 0.f, 0.f);
        __syncthreads();

        // predicated LDS scatter-add (ds_add_f32)
        const int lo = h * HALF_;
        if ((unsigned)(v - lo) < (unsigned)HALF_)
            atomicAdd(&cp[v - lo], val);
        __syncthreads();

        // stream this half of the row: out = pg*dist + copyp (copyp already scaled)
        const int base4 = h * HALF4_;
        for (int i = tid; i < HALF4_; i += 512) {
            const int g4 = base4 + i;
            float4 r = cp4[i];
            if (g4 < V4_) {            // pad region (g4 >= 8000) has no dist
                const float4 d = dist4[g4];
                r.x = fmaf(pg, d.x, r.x);
                r.y = fmaf(pg, d.y, r.y);
                r.z = fmaf(pg, d.z, r.z);
                r.w = fmaf(pg, d.w, r.w);
            }
            out4[g4] = r;
        }
        __syncthreads();               // cp reads done before next zero pass
    }
}

extern "C" void kernel_launch(void* const* d_in, const int* in_sizes, int n_in,
                              void* d_out, int out_size, void* d_ws, size_t ws_size,
                              hipStream_t stream)
{
    const float* dist    = (const float*)d_in[0]; // (B, L_DEC, V)
    const float* p_gen   = (const float*)d_in[1]; // (B, L_DEC, 1)
    const float* alph    = (const float*)d_in[2]; // (B, L_SRC, L_DEC)
    // d_in[3] = batch_vocab (shape only)
    const int*   pointer = (const int*)d_in[4];   // (B, L_SRC)
    float* out = (float*)d_out;                   // (B, L_DEC, V_EXT)

    copynet_fused<<<B_ * L_DEC_, 512, 0, stream>>>(dist, p_gen, alph, pointer, out);
}